// Round 10
// baseline (202.157 us; speedup 1.0000x reference)
//
#include <hip/hip_runtime.h>
#include <hip/hip_bf16.h>
#include <math.h>

#define B_ 4
#define S_ 1024
#define E_ 512
#define H_ 8
#define DK_ 64

typedef short bf16x8 __attribute__((ext_vector_type(8)));
typedef float f32x4 __attribute__((ext_vector_type(4)));

#define MFMA16(a, b, c) __builtin_amdgcn_mfma_f32_16x16x32_bf16((a), (b), (c), 0, 0, 0)
#define cfence() asm volatile("" ::: "memory")

__device__ __forceinline__ void gl_lds16(const void* gptr, void* lptr) {
    __builtin_amdgcn_global_load_lds(
        (const __attribute__((address_space(1))) unsigned int*)gptr,
        (__attribute__((address_space(3))) unsigned int*)lptr,
        16, 0, 0);
}

__device__ __forceinline__ unsigned short bf16_bits(float v) {
    __hip_bfloat16 h = __float2bfloat16(v);
    return *(unsigned short*)&h;
}

// ---------------------------------------------------------------------------
// prep: fp32->bf16 converts (blocks 0..3583) + conv-bias precompute
// (blocks 3584..7679). biasS[b,g,i,j] = raw conv-bias bf16 (0.125 lives in
// the Q projection); masked -> 0xFF80 (bf16 -inf in-band magic).
// ---------------------------------------------------------------------------
__global__ __launch_bounds__(256) void prep(
    const float* __restrict__ q, const float* __restrict__ k, const float* __restrict__ v,
    const float* __restrict__ wq, const float* __restrict__ wk,
    const float* __restrict__ wv, const float* __restrict__ wo,
    const float* __restrict__ dist, const int* __restrict__ mask,
    const float* __restrict__ cw1, const float* __restrict__ cb1,
    const float* __restrict__ cw2, const float* __restrict__ cb2,
    __hip_bfloat16* qc, __hip_bfloat16* kc, __hip_bfloat16* vc,
    __hip_bfloat16* wqc, __hip_bfloat16* wkc, __hip_bfloat16* wvc, __hip_bfloat16* woc,
    __hip_bfloat16* __restrict__ biasS) {
    const int blk = blockIdx.x;
    const int tid = threadIdx.x;
    if (blk >= 3584) {
        const int bi = blk - 3584;
        const int b = bi >> 10, i = bi & 1023;
        const int j0 = tid * 4;
        const size_t dbase = ((size_t)b * 1024 + i) * 1024 + j0;
        float4 d4 = *(const float4*)(dist + dbase);
        int4 m4 = *(const int4*)(mask + dbase);
        float dv[4] = {d4.x, d4.y, d4.z, d4.w};
        int mv[4] = {m4.x, m4.y, m4.z, m4.w};
        float tt[4][8];
#pragma unroll
        for (int e = 0; e < 4; ++e)
#pragma unroll
            for (int h = 0; h < 8; ++h)
                tt[e][h] = fmaxf(fmaf(dv[e], cw1[h], cb1[h]), 0.f);
#pragma unroll
        for (int g = 0; g < 8; ++g) {
            const float c2 = cb2[g];
            union { unsigned short us[4]; uint2 u2; } o;
#pragma unroll
            for (int e = 0; e < 4; ++e) {
                float bv = c2;
#pragma unroll
                for (int h = 0; h < 8; ++h) bv = fmaf(tt[e][h], cw2[g * 8 + h], bv);
                unsigned short u = bf16_bits(bv);
                if (mv[e] == 0) u = 0xFF80u;
                o.us[e] = u;
            }
            *(uint2*)(biasS + ((size_t)(b * 8 + g) * 1024 + i) * 1024 + j0) = o.u2;
        }
        return;
    }
    const float* src;
    __hip_bfloat16* dst;
    int base;
    if (blk < 1024)      { src = q; dst = qc; base = blk; }
    else if (blk < 2048) { src = k; dst = kc; base = blk - 1024; }
    else if (blk < 3072) { src = v; dst = vc; base = blk - 2048; }
    else {
        const int wz = (blk - 3072) >> 7;
        base = (blk - 3072) & 127;
        switch (wz) {
            case 0: src = wq; dst = wqc; break;
            case 1: src = wk; dst = wkc; break;
            case 2: src = wv; dst = wvc; break;
            default: src = wo; dst = woc; break;
        }
    }
    const int idx = (base * 256 + tid) * 8;
    float4 a = *(const float4*)(src + idx);
    float4 bb = *(const float4*)(src + idx + 4);
    union { __hip_bfloat16 h[8]; uint4 u; } o;
    o.h[0] = __float2bfloat16(a.x);  o.h[1] = __float2bfloat16(a.y);
    o.h[2] = __float2bfloat16(a.z);  o.h[3] = __float2bfloat16(a.w);
    o.h[4] = __float2bfloat16(bb.x); o.h[5] = __float2bfloat16(bb.y);
    o.h[6] = __float2bfloat16(bb.z); o.h[7] = __float2bfloat16(bb.w);
    *(uint4*)(dst + idx) = o.u;
}

// ---------------------------------------------------------------------------
// MFMA GEMM core, BK=128 (4 K-chunks), 256-B LDS rows, XOR-swizzle (mask 15).
// ---------------------------------------------------------------------------
template <int NROWS_W, int NT>
__device__ __forceinline__ void gemm_core128(const __hip_bfloat16* A, const __hip_bfloat16* W,
                                             char* sA, char* sW, int m0, int n0,
                                             f32x4 acc[4][NT]) {
    const int t = threadIdx.x;
    const int w = t >> 6, lane = t & 63;
    const int wm = (w >> 1) * 64, wn = (w & 1) * (NT * 16);
    const int g = lane >> 4, ln = lane & 15;

    for (int kc = 0; kc < 4; ++kc) {
        __syncthreads();
#pragma unroll
        for (int i = 0; i < 8; ++i) {
            int L = (i * 4 + w) * 64 + lane;
            int r = L >> 4, cs = L & 15;
            int c = cs ^ (r & 15);
            gl_lds16((const char*)A + (size_t)(m0 + r) * 1024 + kc * 256 + c * 16,
                     sA + (i * 4 + w) * 1024);
        }
#pragma unroll
        for (int i = 0; i < NROWS_W / 16; ++i) {
            int L = (i * 4 + w) * 64 + lane;
            int r = L >> 4, cs = L & 15;
            int c = cs ^ (r & 15);
            gl_lds16((const char*)W + (size_t)(n0 + r) * 1024 + kc * 256 + c * 16,
                     sW + (i * 4 + w) * 1024);
        }
        __syncthreads();
#pragma unroll
        for (int ks = 0; ks < 4; ++ks) {
            bf16x8 af[4], bf[NT];
#pragma unroll
            for (int mt = 0; mt < 4; ++mt) {
                int m = wm + mt * 16 + ln;
                int c = ks * 4 + g;
                af[mt] = *(const bf16x8*)(sA + m * 256 + (c ^ (m & 15)) * 16);
            }
#pragma unroll
            for (int nt = 0; nt < NT; ++nt) {
                int n = wn + nt * 16 + ln;
                int c = ks * 4 + g;
                bf[nt] = *(const bf16x8*)(sW + n * 256 + (c ^ (n & 15)) * 16);
            }
#pragma unroll
            for (int mt = 0; mt < 4; ++mt)
#pragma unroll
                for (int nt = 0; nt < NT; ++nt)
                    acc[mt][nt] = MFMA16(af[mt], bf[nt], acc[mt][nt]);
        }
    }
}

// Projections, 128x64 tiles (one head per tile), BK=128, 48 KB LDS ->
// 3 blocks/CU, grid (8, 32, 3) = 768 = one full round.
// z: 0=q (x0.125 folded), 1=k split-head [B,H,S,DK]; 2=v transposed [B,H,DK,S].
__global__ __launch_bounds__(256) void proj_gemm(
    const __hip_bfloat16* __restrict__ qc, const __hip_bfloat16* __restrict__ kc,
    const __hip_bfloat16* __restrict__ vc,
    const __hip_bfloat16* __restrict__ wqc, const __hip_bfloat16* __restrict__ wkc,
    const __hip_bfloat16* __restrict__ wvc,
    const float* __restrict__ bq, const float* __restrict__ bk, const float* __restrict__ bv,
    __hip_bfloat16* qbh, __hip_bfloat16* kbh, __hip_bfloat16* vt) {
    __shared__ char smem[49152];
    char* sA = smem;
    char* sW = smem + 32768;
    const int z = blockIdx.z;
    const __hip_bfloat16* A;
    const __hip_bfloat16* W;
    const float* bias;
    __hip_bfloat16* dst;
    float scale;
    if (z == 0)      { A = qc; W = wqc; bias = bq; dst = qbh; scale = 0.125f; }
    else if (z == 1) { A = kc; W = wkc; bias = bk; dst = kbh; scale = 1.f; }
    else             { A = vc; W = wvc; bias = bv; dst = vt;  scale = 1.f; }

    const int m0 = blockIdx.y * 128, n0 = blockIdx.x * 64;
    f32x4 acc[4][2] = {};
    gemm_core128<64, 2>(A, W, sA, sW, m0, n0, acc);
    __syncthreads();  // done with sA/sW; reuse for repack

    const int t = threadIdx.x;
    const int w = t >> 6, lane = t & 63;
    const int wm = (w >> 1) * 64, wn = (w & 1) * 32;
    const int g = lane >> 4, ln = lane & 15;
    const int b = m0 >> 10;
    const int h = n0 >> 6;
    float bv2[2];
#pragma unroll
    for (int nt = 0; nt < 2; ++nt) bv2[nt] = bias[n0 + wn + nt * 16 + ln];

    __hip_bfloat16* T = (__hip_bfloat16*)smem;
    if (z != 2) {
        // rows padded to 72 bf16 (144 B, 16B-aligned for b128 reads)
#pragma unroll
        for (int mt = 0; mt < 4; ++mt)
#pragma unroll
            for (int nt = 0; nt < 2; ++nt)
#pragma unroll
                for (int r = 0; r < 4; ++r)
                    T[(wm + mt * 16 + g * 4 + r) * 72 + wn + nt * 16 + ln] =
                        __float2bfloat16((acc[mt][nt][r] + bv2[nt]) * scale);
        __syncthreads();
        // thread = half-row (64 B); dst row = 128 B contiguous (one head)
        const int lr = t >> 1, half = t & 1;
        const char* srow = (const char*)T + lr * 144 + half * 64;
        char* gdst = (char*)dst +
                     (((size_t)(b * 8 + h) * 1024 + (m0 & 1023) + lr) * 64) * 2 + half * 64;
#pragma unroll
        for (int j = 0; j < 4; ++j)
            *(uint4*)(gdst + j * 16) = *(const uint4*)(srow + j * 16);
    } else {
        // rows padded to 66 bf16 (132 B, odd word stride -> conflict-free cols)
#pragma unroll
        for (int mt = 0; mt < 4; ++mt)
#pragma unroll
            for (int nt = 0; nt < 2; ++nt)
#pragma unroll
                for (int r = 0; r < 4; ++r)
                    T[(wm + mt * 16 + g * 4 + r) * 66 + wn + nt * 16 + ln] =
                        __float2bfloat16(acc[mt][nt][r] + bv2[nt]);
        __syncthreads();
        // transposed readback: thread = (dk, 32-row chunk), 64 B contiguous out
        const int dk = t >> 2, a2 = t & 3;
        union { __hip_bfloat16 hh[32]; uint4 u[4]; } P;
#pragma unroll
        for (int i = 0; i < 32; ++i)
            P.hh[i] = T[(a2 * 32 + i) * 66 + dk];
        char* gdst = (char*)vt +
                     (((size_t)(b * 8 + h) * 64 + dk) * 1024 + (m0 & 1023) + a2 * 32) * 2;
#pragma unroll
        for (int j = 0; j < 4; ++j)
            *(uint4*)(gdst + j * 16) = P.u[j];
    }
}

// Output GEMM: out[4096,512] fp32, 128x64 tile, BK=128. grid (8, 32).
__global__ __launch_bounds__(256) void out_gemm(
    const __hip_bfloat16* __restrict__ X, const __hip_bfloat16* __restrict__ woc,
    const float* __restrict__ bo, float* __restrict__ out) {
    __shared__ char smem[49152];
    char* sA = smem;
    char* sW = smem + 32768;
    const int m0 = blockIdx.y * 128, n0 = blockIdx.x * 64;
    f32x4 acc[4][2] = {};
    gemm_core128<64, 2>(X, woc, sA, sW, m0, n0, acc);

    const int t = threadIdx.x;
    const int w = t >> 6, lane = t & 63;
    const int wm = (w >> 1) * 64, wn = (w & 1) * 32;
    const int g = lane >> 4, ln = lane & 15;
    float bv2[2];
#pragma unroll
    for (int nt = 0; nt < 2; ++nt) bv2[nt] = bo[n0 + wn + nt * 16 + ln];
#pragma unroll
    for (int mt = 0; mt < 4; ++mt)
#pragma unroll
        for (int nt = 0; nt < 2; ++nt)
#pragma unroll
            for (int r = 0; r < 4; ++r) {
                int m = m0 + wm + mt * 16 + g * 4 + r;
                int f = n0 + wn + nt * 16 + ln;
                out[(size_t)m * 512 + f] = acc[mt][nt][r] + bv2[nt];
            }
}

// ---------------------------------------------------------------------------
// Flash-decode split-K attention, double-buffered K/V LDS + bias register
// prefetch -> ONE barrier per 64-key iteration; the barrier at iter i drains
// loads issued at iter i-1 (a full compute phase of latency hiding).
// grid (16, 32, 2): (q-tile, b*h, key-split). Partial O (bf16) + (m,l).
// ---------------------------------------------------------------------------
__global__ __launch_bounds__(256) void attn_split(
    const __hip_bfloat16* __restrict__ Qb, const __hip_bfloat16* __restrict__ Kb,
    const __hip_bfloat16* __restrict__ Vt, const __hip_bfloat16* __restrict__ biasS,
    __hip_bfloat16* __restrict__ Op, float2* __restrict__ Ml) {
    __shared__ char sK[2][8192];     // 64 keys x 128 B, double-buffered
    __shared__ char sV[2][8192];     // 64 dk x 128 B window, double-buffered
    __shared__ char sScP[4][4352];   // per-wave: f32 scores 16x66 OR bf16 P 16x72
    __shared__ float sBr[4][16];

    const int t = threadIdx.x, w = t >> 6, lane = t & 63;
    const int g = lane >> 4, ln = lane & 15;
    const int qr = lane >> 2, a = lane & 3;
    const int bh = blockIdx.y;
    const int q0 = blockIdx.x * 64;
    const int spl = blockIdx.z;
    const int kt0 = spl * 512;

    float* sc = (float*)(sScP[w]);
    __hip_bfloat16* sp = (__hip_bfloat16*)(sScP[w]);

    bf16x8 qf[2];
    {
        const char* qbase = (const char*)Qb + ((size_t)bh * 1024 + q0 + w * 16 + ln) * 128;
        qf[0] = *(const bf16x8*)(qbase + g * 16);
        qf[1] = *(const bf16x8*)(qbase + 64 + g * 16);
    }

    // hoisted K/V/bias addresses (incremented each staging round)
    const char* kaddr[2];
    const char* vaddr[2];
#pragma unroll
    for (int i = 0; i < 2; ++i) {
        int L = (i * 4 + w) * 64 + lane;
        int r = L >> 3, cs = L & 7;
        int c = cs ^ (r & 7);
        kaddr[i] = (const char*)Kb + (size_t)bh * 131072 + (size_t)(kt0 + r) * 128 + c * 16;
        vaddr[i] = (const char*)Vt + (size_t)bh * 131072 + (size_t)r * 2048 + (size_t)kt0 * 2 + c * 16;
    }
    const char* baddr =
        (const char*)(biasS + ((size_t)bh * 1024 + q0 + w * 16 + qr) * 1024 + kt0 + a * 16);

    float m_st = -1e30f, l_st = 0.f;
    f32x4 O[4] = {};

    // prologue: stage tile 0 into buffer 0, bias 0 into regs
#pragma unroll
    for (int i = 0; i < 2; ++i) {
        gl_lds16(kaddr[i], sK[0] + (i * 4 + w) * 1024);
        gl_lds16(vaddr[i], sV[0] + (i * 4 + w) * 1024);
        kaddr[i] += 8192;
        vaddr[i] += 128;
    }
    union bbu { uint4 u[2]; unsigned short us[16]; };
    bbu bb;
    bb.u[0] = *(const uint4*)baddr;
    bb.u[1] = *(const uint4*)(baddr + 16);
    baddr += 128;

    for (int it = 0; it < 8; ++it) {
        const int cur = it & 1;
        __syncthreads();  // drains vmcnt: buf[cur] + bb are ready
        bbu bbc = bb;     // capture before overwriting with prefetch
        if (it < 7) {
#pragma unroll
            for (int i = 0; i < 2; ++i) {
                gl_lds16(kaddr[i], sK[cur ^ 1] + (i * 4 + w) * 1024);
                gl_lds16(vaddr[i], sV[cur ^ 1] + (i * 4 + w) * 1024);
                kaddr[i] += 8192;
                vaddr[i] += 128;
            }
            bb.u[0] = *(const uint4*)baddr;
            bb.u[1] = *(const uint4*)(baddr + 16);
            baddr += 128;
        }

        // QK^T (C-layout); q pre-scaled by 0.125
        f32x4 scv[4] = {};
#pragma unroll
        for (int tt = 0; tt < 4; ++tt)
#pragma unroll
            for (int ks = 0; ks < 2; ++ks) {
                int key = tt * 16 + ln;
                int c = ks * 4 + g;
                bf16x8 kf = *(const bf16x8*)(sK[cur] + key * 128 + (c ^ (key & 7)) * 16);
                scv[tt] = MFMA16(qf[ks], kf, scv[tt]);
            }

        cfence();
#pragma unroll
        for (int tt = 0; tt < 4; ++tt)
#pragma unroll
            for (int r = 0; r < 4; ++r)
                sc[(g * 4 + r) * 66 + tt * 16 + ln] = scv[tt][r];
        cfence();

        float sr[16];
        {
            const float* scrow = sc + qr * 66 + a * 16;
#pragma unroll
            for (int j = 0; j < 8; ++j) {
                float2 v2 = *(const float2*)(scrow + j * 2);
                sr[j * 2] = v2.x; sr[j * 2 + 1] = v2.y;
            }
        }
        cfence();

        // apply precomputed bias + magic mask + max
        float mx = -1e30f;
#pragma unroll
        for (int e = 0; e < 16; ++e) {
            unsigned int bits = bbc.us[e];
            float f = __uint_as_float(bits << 16);
            float s = sr[e] * f;
            s = (bits == 0xFF80u) ? -1e9f : s;
            sr[e] = s;
            mx = fmaxf(mx, s);
        }
        mx = fmaxf(mx, __shfl_xor(mx, 1));
        mx = fmaxf(mx, __shfl_xor(mx, 2));
        const float mnew = fmaxf(m_st, mx);
        const float alpha = __expf(m_st - mnew);
        m_st = mnew;
        float rs = 0.f;
        union { __hip_bfloat16 hh16[16]; uint4 u[2]; } Pk;
#pragma unroll
        for (int i = 0; i < 16; ++i) {
            float p = __expf(sr[i] - mnew);
            rs += p;
            Pk.hh16[i] = __float2bfloat16(p);
        }
        rs += __shfl_xor(rs, 1);
        rs += __shfl_xor(rs, 2);
        l_st = l_st * alpha + rs;

        *(uint4*)(sp + qr * 72 + a * 16) = Pk.u[0];
        *(uint4*)(sp + qr * 72 + a * 16 + 8) = Pk.u[1];
        cfence();

        if (a == 0) sBr[w][qr] = alpha;
        float al4[4];
#pragma unroll
        for (int r = 0; r < 4; ++r) al4[r] = sBr[w][g * 4 + r];
#pragma unroll
        for (int tt = 0; tt < 4; ++tt)
#pragma unroll
            for (int r = 0; r < 4; ++r) O[tt][r] *= al4[r];

        // PV
#pragma unroll
        for (int ks = 0; ks < 2; ++ks) {
            bf16x8 pf = *(const bf16x8*)(sp + ln * 72 + ks * 32 + g * 8);
#pragma unroll
            for (int tt = 0; tt < 4; ++tt) {
                int dk = tt * 16 + ln;
                int c = ks * 4 + g;
                bf16x8 vf = *(const bf16x8*)(sV[cur] + dk * 128 + (c ^ (dk & 7)) * 16);
                O[tt] = MFMA16(pf, vf, O[tt]);
            }
        }
        cfence();
    }

    // partial epilogue: unnormalized O (bf16) + (m,l) per row
    const size_t rowbase = ((size_t)spl * 32 + bh) * 1024 + q0 + w * 16;
    if (a == 0) {
        float2 ml2; ml2.x = m_st; ml2.y = l_st;
        Ml[rowbase + qr] = ml2;
    }
#pragma unroll
    for (int r = 0; r < 4; ++r) {
        const int q = g * 4 + r;
#pragma unroll
        for (int tt = 0; tt < 4; ++tt)
            Op[(rowbase + q) * 64 + tt * 16 + ln] = __float2bfloat16(O[tt][r]);
    }
}

// Merge the two key-splits (bf16 partials, f32 math).
// grid 4096 x 256 thr; thread = (row, dk pair).
__global__ __launch_bounds__(256) void combine(
    const __hip_bfloat16* __restrict__ Op, const float2* __restrict__ Ml,
    __hip_bfloat16* __restrict__ X) {
    const int idx = blockIdx.x * 256 + threadIdx.x;
    const int row = idx >> 5;
    const int pr = (idx & 31) * 2;
    float2 ml1 = Ml[row], ml2 = Ml[32768 + row];
    float m = fmaxf(ml1.x, ml2.x);
    float w1 = __expf(ml1.x - m), w2 = __expf(ml2.x - m);
    float inv = 1.f / fmaf(ml1.y, w1, ml2.y * w2);
    unsigned int u1 = *(const unsigned int*)(Op + (size_t)row * 64 + pr);
    unsigned int u2 = *(const unsigned int*)(Op + ((size_t)32768 + row) * 64 + pr);
    float o1x = __uint_as_float(u1 << 16), o1y = __uint_as_float(u1 & 0xFFFF0000u);
    float o2x = __uint_as_float(u2 << 16), o2y = __uint_as_float(u2 & 0xFFFF0000u);
    float x0 = fmaf(o1x, w1, o2x * w2) * inv;
    float x1 = fmaf(o1y, w1, o2y * w2) * inv;
    const int bh = row >> 10, s = row & 1023, b = bh >> 3, h = bh & 7;
    union { __hip_bfloat16 hh[2]; unsigned int u; } o;
    o.hh[0] = __float2bfloat16(x0);
    o.hh[1] = __float2bfloat16(x1);
    *(unsigned int*)(X + ((size_t)(b * 1024 + s)) * 512 + h * 64 + pr) = o.u;
}

extern "C" void kernel_launch(void* const* d_in, const int* in_sizes, int n_in,
                              void* d_out, int out_size, void* d_ws, size_t ws_size,
                              hipStream_t stream) {
    (void)in_sizes; (void)n_in; (void)out_size; (void)ws_size;
    const float* query = (const float*)d_in[0];
    const float* key   = (const float*)d_in[1];
    const float* value = (const float*)d_in[2];
    const float* dist  = (const float*)d_in[3];
    const int*   mask  = (const int*)d_in[4];
    const float* Wq = (const float*)d_in[5];
    const float* bq = (const float*)d_in[6];
    const float* Wk = (const float*)d_in[7];
    const float* bk = (const float*)d_in[8];
    const float* Wv = (const float*)d_in[9];
    const float* bv = (const float*)d_in[10];
    const float* Wo = (const float*)d_in[11];
    const float* bo = (const float*)d_in[12];
    const float* cw1 = (const float*)d_in[13];
    const float* cb1 = (const float*)d_in[14];
    const float* cw2 = (const float*)d_in[15];
    const float* cb2 = (const float*)d_in[16];
    float* out = (float*)d_out;

    char* ws = (char*)d_ws;
    const size_t MB = 1 << 20;
    __hip_bfloat16* qc  = (__hip_bfloat16*)(ws + 0 * MB);
    __hip_bfloat16* kc  = (__hip_bfloat16*)(ws + 4 * MB);
    __hip_bfloat16* vc  = (__hip_bfloat16*)(ws + 8 * MB);
    __hip_bfloat16* wqc = (__hip_bfloat16*)(ws + 12 * MB);
    __hip_bfloat16* wkc = (__hip_bfloat16*)(ws + 12 * MB + 512 * 1024);
    __hip_bfloat16* wvc = (__hip_bfloat16*)(ws + 13 * MB);
    __hip_bfloat16* woc = (__hip_bfloat16*)(ws + 13 * MB + 512 * 1024);
    __hip_bfloat16* qbh = (__hip_bfloat16*)(ws + 14 * MB);
    __hip_bfloat16* kbh = (__hip_bfloat16*)(ws + 18 * MB);
    __hip_bfloat16* vt  = (__hip_bfloat16*)(ws + 22 * MB);
    __hip_bfloat16* x   = (__hip_bfloat16*)(ws + 26 * MB);
    __hip_bfloat16* bS  = (__hip_bfloat16*)(ws + 32 * MB);  // 64 MB
    __hip_bfloat16* Op  = (__hip_bfloat16*)(ws + 96 * MB);  // 8.4 MB
    float2*         Ml  = (float2*)(ws + 112 * MB);         // 512 KB

    hipLaunchKernelGGL(prep, dim3(7680), dim3(256), 0, stream,
                       query, key, value, Wq, Wk, Wv, Wo, dist, mask,
                       cw1, cb1, cw2, cb2,
                       qc, kc, vc, wqc, wkc, wvc, woc, bS);
    hipLaunchKernelGGL(proj_gemm, dim3(8, 32, 3), dim3(256), 0, stream,
                       qc, kc, vc, wqc, wkc, wvc, bq, bk, bv, qbh, kbh, vt);
    hipLaunchKernelGGL(attn_split, dim3(16, 32, 2), dim3(256), 0, stream,
                       qbh, kbh, vt, bS, Op, Ml);
    hipLaunchKernelGGL(combine, dim3(4096), dim3(256), 0, stream, Op, Ml, x);
    hipLaunchKernelGGL(out_gemm, dim3(8, 32), dim3(256), 0, stream,
                       x, woc, bo, out);
}

// Round 11
// 192.954 us; speedup vs baseline: 1.0477x; 1.0477x over previous
//
#include <hip/hip_runtime.h>
#include <hip/hip_bf16.h>
#include <math.h>

#define B_ 4
#define S_ 1024
#define E_ 512
#define H_ 8
#define DK_ 64

typedef short bf16x8 __attribute__((ext_vector_type(8)));
typedef float f32x4 __attribute__((ext_vector_type(4)));

#define MFMA16(a, b, c) __builtin_amdgcn_mfma_f32_16x16x32_bf16((a), (b), (c), 0, 0, 0)
#define cfence() asm volatile("" ::: "memory")

__device__ __forceinline__ void gl_lds16(const void* gptr, void* lptr) {
    __builtin_amdgcn_global_load_lds(
        (const __attribute__((address_space(1))) unsigned int*)gptr,
        (__attribute__((address_space(3))) unsigned int*)lptr,
        16, 0, 0);
}

__device__ __forceinline__ unsigned short bf16_bits(float v) {
    __hip_bfloat16 h = __float2bfloat16(v);
    return *(unsigned short*)&h;
}

// ---------------------------------------------------------------------------
// prep: fp32->bf16 converts (blocks 0..3583) + conv-bias precompute
// (blocks 3584..7679). biasS[b,g,i,j] = raw conv-bias bf16 (0.125 lives in
// the Q projection); masked -> 0xFF80 (bf16 -inf in-band magic).
// ---------------------------------------------------------------------------
__global__ __launch_bounds__(256) void prep(
    const float* __restrict__ q, const float* __restrict__ k, const float* __restrict__ v,
    const float* __restrict__ wq, const float* __restrict__ wk,
    const float* __restrict__ wv, const float* __restrict__ wo,
    const float* __restrict__ dist, const int* __restrict__ mask,
    const float* __restrict__ cw1, const float* __restrict__ cb1,
    const float* __restrict__ cw2, const float* __restrict__ cb2,
    __hip_bfloat16* qc, __hip_bfloat16* kc, __hip_bfloat16* vc,
    __hip_bfloat16* wqc, __hip_bfloat16* wkc, __hip_bfloat16* wvc, __hip_bfloat16* woc,
    __hip_bfloat16* __restrict__ biasS) {
    const int blk = blockIdx.x;
    const int tid = threadIdx.x;
    if (blk >= 3584) {
        const int bi = blk - 3584;
        const int b = bi >> 10, i = bi & 1023;
        const int j0 = tid * 4;
        const size_t dbase = ((size_t)b * 1024 + i) * 1024 + j0;
        float4 d4 = *(const float4*)(dist + dbase);
        int4 m4 = *(const int4*)(mask + dbase);
        float dv[4] = {d4.x, d4.y, d4.z, d4.w};
        int mv[4] = {m4.x, m4.y, m4.z, m4.w};
        float tt[4][8];
#pragma unroll
        for (int e = 0; e < 4; ++e)
#pragma unroll
            for (int h = 0; h < 8; ++h)
                tt[e][h] = fmaxf(fmaf(dv[e], cw1[h], cb1[h]), 0.f);
#pragma unroll
        for (int g = 0; g < 8; ++g) {
            const float c2 = cb2[g];
            union { unsigned short us[4]; uint2 u2; } o;
#pragma unroll
            for (int e = 0; e < 4; ++e) {
                float bv = c2;
#pragma unroll
                for (int h = 0; h < 8; ++h) bv = fmaf(tt[e][h], cw2[g * 8 + h], bv);
                unsigned short u = bf16_bits(bv);
                if (mv[e] == 0) u = 0xFF80u;
                o.us[e] = u;
            }
            *(uint2*)(biasS + ((size_t)(b * 8 + g) * 1024 + i) * 1024 + j0) = o.u2;
        }
        return;
    }
    const float* src;
    __hip_bfloat16* dst;
    int base;
    if (blk < 1024)      { src = q; dst = qc; base = blk; }
    else if (blk < 2048) { src = k; dst = kc; base = blk - 1024; }
    else if (blk < 3072) { src = v; dst = vc; base = blk - 2048; }
    else {
        const int wz = (blk - 3072) >> 7;
        base = (blk - 3072) & 127;
        switch (wz) {
            case 0: src = wq; dst = wqc; break;
            case 1: src = wk; dst = wkc; break;
            case 2: src = wv; dst = wvc; break;
            default: src = wo; dst = woc; break;
        }
    }
    const int idx = (base * 256 + tid) * 8;
    float4 a = *(const float4*)(src + idx);
    float4 bb = *(const float4*)(src + idx + 4);
    union { __hip_bfloat16 h[8]; uint4 u; } o;
    o.h[0] = __float2bfloat16(a.x);  o.h[1] = __float2bfloat16(a.y);
    o.h[2] = __float2bfloat16(a.z);  o.h[3] = __float2bfloat16(a.w);
    o.h[4] = __float2bfloat16(bb.x); o.h[5] = __float2bfloat16(bb.y);
    o.h[6] = __float2bfloat16(bb.z); o.h[7] = __float2bfloat16(bb.w);
    *(uint4*)(dst + idx) = o.u;
}

// ---------------------------------------------------------------------------
// MFMA GEMM core, BK=64, DOUBLE-BUFFERED: stage kc+1 while computing kc.
// 128-B LDS rows, XOR swizzle mask 7. sA = 2 x 16 KB; sW = 2 x NROWS_W*128 B.
// One barrier per kc; it drains loads issued a full compute phase earlier.
// ---------------------------------------------------------------------------
template <int NROWS_W, int NT>
__device__ __forceinline__ void gemm_core64(const __hip_bfloat16* A, const __hip_bfloat16* W,
                                            char* sA, char* sW, int m0, int n0,
                                            f32x4 acc[4][NT]) {
    const int t = threadIdx.x;
    const int w = t >> 6, lane = t & 63;
    const int wm = (w >> 1) * 64, wn = (w & 1) * (NT * 16);
    const int g = lane >> 4, ln = lane & 15;
    const int WB = NROWS_W * 128;

    // hoisted staging addresses, incremented 128 B per kc
    const char* aaddr[4];
    const char* waddr[NROWS_W / 32];
#pragma unroll
    for (int i = 0; i < 4; ++i) {
        int L = (i * 4 + w) * 64 + lane;
        int r = L >> 3, cs = L & 7;
        int c = cs ^ (r & 7);
        aaddr[i] = (const char*)A + (size_t)(m0 + r) * 1024 + c * 16;
    }
#pragma unroll
    for (int i = 0; i < NROWS_W / 32; ++i) {
        int L = (i * 4 + w) * 64 + lane;
        int r = L >> 3, cs = L & 7;
        int c = cs ^ (r & 7);
        waddr[i] = (const char*)W + (size_t)(n0 + r) * 1024 + c * 16;
    }

    // prologue: stage kc=0 into buffer 0
#pragma unroll
    for (int i = 0; i < 4; ++i) {
        gl_lds16(aaddr[i], sA + (i * 4 + w) * 1024);
        aaddr[i] += 128;
    }
#pragma unroll
    for (int i = 0; i < NROWS_W / 32; ++i) {
        gl_lds16(waddr[i], sW + (i * 4 + w) * 1024);
        waddr[i] += 128;
    }

    for (int kc = 0; kc < 8; ++kc) {
        const int cur = kc & 1;
        __syncthreads();  // buf[cur] ready (loads were issued one kc ago)
        if (kc < 7) {
            char* nA = sA + (cur ^ 1) * 16384;
            char* nW = sW + (cur ^ 1) * WB;
#pragma unroll
            for (int i = 0; i < 4; ++i) {
                gl_lds16(aaddr[i], nA + (i * 4 + w) * 1024);
                aaddr[i] += 128;
            }
#pragma unroll
            for (int i = 0; i < NROWS_W / 32; ++i) {
                gl_lds16(waddr[i], nW + (i * 4 + w) * 1024);
                waddr[i] += 128;
            }
        }
        const char* cA = sA + cur * 16384;
        const char* cW = sW + cur * WB;
#pragma unroll
        for (int ks = 0; ks < 2; ++ks) {
            bf16x8 af[4], bf[NT];
#pragma unroll
            for (int mt = 0; mt < 4; ++mt) {
                int m = wm + mt * 16 + ln;
                int c = ks * 4 + g;
                af[mt] = *(const bf16x8*)(cA + m * 128 + (c ^ (m & 7)) * 16);
            }
#pragma unroll
            for (int nt = 0; nt < NT; ++nt) {
                int n = wn + nt * 16 + ln;
                int c = ks * 4 + g;
                bf[nt] = *(const bf16x8*)(cW + n * 128 + (c ^ (n & 7)) * 16);
            }
#pragma unroll
            for (int mt = 0; mt < 4; ++mt)
#pragma unroll
                for (int nt = 0; nt < NT; ++nt)
                    acc[mt][nt] = MFMA16(af[mt], bf[nt], acc[mt][nt]);
        }
    }
}

// Projections, 128x128 tiles, BK=64 dbuf, 64 KB LDS. grid (4, 32, 3).
// z: 0=q (x0.125 folded), 1=k split-head [B,H,S,DK]; 2=v transposed [B,H,DK,S].
__global__ __launch_bounds__(256) void proj_gemm(
    const __hip_bfloat16* __restrict__ qc, const __hip_bfloat16* __restrict__ kc,
    const __hip_bfloat16* __restrict__ vc,
    const __hip_bfloat16* __restrict__ wqc, const __hip_bfloat16* __restrict__ wkc,
    const __hip_bfloat16* __restrict__ wvc,
    const float* __restrict__ bq, const float* __restrict__ bk, const float* __restrict__ bv,
    __hip_bfloat16* qbh, __hip_bfloat16* kbh, __hip_bfloat16* vt) {
    __shared__ char smem[65536];
    char* sA = smem;              // 2 x 16 KB
    char* sW = smem + 32768;      // 2 x 16 KB
    const int z = blockIdx.z;
    const __hip_bfloat16* A;
    const __hip_bfloat16* W;
    const float* bias;
    __hip_bfloat16* dst;
    float scale;
    if (z == 0)      { A = qc; W = wqc; bias = bq; dst = qbh; scale = 0.125f; }
    else if (z == 1) { A = kc; W = wkc; bias = bk; dst = kbh; scale = 1.f; }
    else             { A = vc; W = wvc; bias = bv; dst = vt;  scale = 1.f; }

    const int m0 = blockIdx.y * 128, n0 = blockIdx.x * 128;
    f32x4 acc[4][4] = {};
    gemm_core64<128, 4>(A, W, sA, sW, m0, n0, acc);
    __syncthreads();  // done with staging buffers; reuse smem for repack

    const int t = threadIdx.x;
    const int w = t >> 6, lane = t & 63;
    const int wm = (w >> 1) * 64, wn = (w & 1) * 64;
    const int g = lane >> 4, ln = lane & 15;
    const int b = m0 >> 10;
    float bv4[4];
#pragma unroll
    for (int nt = 0; nt < 4; ++nt) bv4[nt] = bias[n0 + wn + nt * 16 + ln];

    __hip_bfloat16* T = (__hip_bfloat16*)smem;
    if (z != 2) {
        // rows padded to 136 bf16 (272 B, 16B-aligned for b128 reads)
#pragma unroll
        for (int p = 0; p < 2; ++p) {
            if (wm == p * 64) {
#pragma unroll
                for (int mt = 0; mt < 4; ++mt)
#pragma unroll
                    for (int nt = 0; nt < 4; ++nt)
#pragma unroll
                        for (int r = 0; r < 4; ++r)
                            T[(mt * 16 + g * 4 + r) * 136 + wn + nt * 16 + ln] =
                                __float2bfloat16((acc[mt][nt][r] + bv4[nt]) * scale);
            }
            __syncthreads();
            const int lr = t >> 2, quarter = t & 3;
            const char* srow = (const char*)T + lr * 272 + quarter * 64;
            const int s = (m0 & 1023) + p * 64 + lr;
            const int h = (n0 >> 6) + (quarter >> 1);
            char* gdst = (char*)dst +
                         (((size_t)(b * 8 + h) * 1024 + s) * 64 + (quarter & 1) * 32) * 2;
#pragma unroll
            for (int j = 0; j < 4; ++j)
                *(uint4*)(gdst + j * 16) = *(const uint4*)(srow + j * 16);
            __syncthreads();
        }
    } else {
        // rows padded to 130 bf16 (260 B, odd word stride -> conflict-free cols)
#pragma unroll
        for (int p = 0; p < 2; ++p) {
            if (wm == p * 64) {
#pragma unroll
                for (int mt = 0; mt < 4; ++mt)
#pragma unroll
                    for (int nt = 0; nt < 4; ++nt)
#pragma unroll
                        for (int r = 0; r < 4; ++r)
                            T[(mt * 16 + g * 4 + r) * 130 + wn + nt * 16 + ln] =
                                __float2bfloat16(acc[mt][nt][r] + bv4[nt]);
            }
            __syncthreads();
            const int c = t >> 1, sel = t & 1;
            union { __hip_bfloat16 h[32]; uint4 u[4]; } P;
#pragma unroll
            for (int i = 0; i < 32; ++i)
                P.h[i] = T[(sel * 32 + i) * 130 + c];
            const int h = (n0 >> 6) + (c >> 6), dk = c & 63;
            char* gdst = (char*)vt +
                         (((size_t)(b * 8 + h) * 64 + dk) * 1024 + (m0 & 1023) + p * 64 + sel * 32) * 2;
#pragma unroll
            for (int j = 0; j < 4; ++j)
                *(uint4*)(gdst + j * 16) = P.u[j];
            __syncthreads();
        }
    }
}

// Output GEMM: out[4096,512] fp32, 128x64 tile, BK=64 dbuf, 48 KB LDS.
// grid (8, 32).
__global__ __launch_bounds__(256) void out_gemm(
    const __hip_bfloat16* __restrict__ X, const __hip_bfloat16* __restrict__ woc,
    const float* __restrict__ bo, float* __restrict__ out) {
    __shared__ char smem[49152];
    char* sA = smem;              // 2 x 16 KB
    char* sW = smem + 32768;      // 2 x 8 KB
    const int m0 = blockIdx.y * 128, n0 = blockIdx.x * 64;
    f32x4 acc[4][2] = {};
    gemm_core64<64, 2>(X, woc, sA, sW, m0, n0, acc);

    const int t = threadIdx.x;
    const int w = t >> 6, lane = t & 63;
    const int wm = (w >> 1) * 64, wn = (w & 1) * 32;
    const int g = lane >> 4, ln = lane & 15;
    float bv2[2];
#pragma unroll
    for (int nt = 0; nt < 2; ++nt) bv2[nt] = bo[n0 + wn + nt * 16 + ln];
#pragma unroll
    for (int mt = 0; mt < 4; ++mt)
#pragma unroll
        for (int nt = 0; nt < 2; ++nt)
#pragma unroll
            for (int r = 0; r < 4; ++r) {
                int m = m0 + wm + mt * 16 + g * 4 + r;
                int f = n0 + wn + nt * 16 + ln;
                out[(size_t)m * 512 + f] = acc[mt][nt][r] + bv2[nt];
            }
}

// ---------------------------------------------------------------------------
// Flash-decode split-K attention, double-buffered K/V LDS + bias register
// prefetch -> ONE barrier per 64-key iteration; the barrier at iter i drains
// loads issued at iter i-1 (a full compute phase of latency hiding).
// grid (16, 32, 2): (q-tile, b*h, key-split). Partial O (bf16) + (m,l).
// ---------------------------------------------------------------------------
__global__ __launch_bounds__(256) void attn_split(
    const __hip_bfloat16* __restrict__ Qb, const __hip_bfloat16* __restrict__ Kb,
    const __hip_bfloat16* __restrict__ Vt, const __hip_bfloat16* __restrict__ biasS,
    __hip_bfloat16* __restrict__ Op, float2* __restrict__ Ml) {
    __shared__ char sK[2][8192];     // 64 keys x 128 B, double-buffered
    __shared__ char sV[2][8192];     // 64 dk x 128 B window, double-buffered
    __shared__ char sScP[4][4352];   // per-wave: f32 scores 16x66 OR bf16 P 16x72
    __shared__ float sBr[4][16];

    const int t = threadIdx.x, w = t >> 6, lane = t & 63;
    const int g = lane >> 4, ln = lane & 15;
    const int qr = lane >> 2, a = lane & 3;
    const int bh = blockIdx.y;
    const int q0 = blockIdx.x * 64;
    const int spl = blockIdx.z;
    const int kt0 = spl * 512;

    float* sc = (float*)(sScP[w]);
    __hip_bfloat16* sp = (__hip_bfloat16*)(sScP[w]);

    bf16x8 qf[2];
    {
        const char* qbase = (const char*)Qb + ((size_t)bh * 1024 + q0 + w * 16 + ln) * 128;
        qf[0] = *(const bf16x8*)(qbase + g * 16);
        qf[1] = *(const bf16x8*)(qbase + 64 + g * 16);
    }

    // hoisted K/V/bias addresses (incremented each staging round)
    const char* kaddr[2];
    const char* vaddr[2];
#pragma unroll
    for (int i = 0; i < 2; ++i) {
        int L = (i * 4 + w) * 64 + lane;
        int r = L >> 3, cs = L & 7;
        int c = cs ^ (r & 7);
        kaddr[i] = (const char*)Kb + (size_t)bh * 131072 + (size_t)(kt0 + r) * 128 + c * 16;
        vaddr[i] = (const char*)Vt + (size_t)bh * 131072 + (size_t)r * 2048 + (size_t)kt0 * 2 + c * 16;
    }
    const char* baddr =
        (const char*)(biasS + ((size_t)bh * 1024 + q0 + w * 16 + qr) * 1024 + kt0 + a * 16);

    float m_st = -1e30f, l_st = 0.f;
    f32x4 O[4] = {};

    // prologue: stage tile 0 into buffer 0, bias 0 into regs
#pragma unroll
    for (int i = 0; i < 2; ++i) {
        gl_lds16(kaddr[i], sK[0] + (i * 4 + w) * 1024);
        gl_lds16(vaddr[i], sV[0] + (i * 4 + w) * 1024);
        kaddr[i] += 8192;
        vaddr[i] += 128;
    }
    union bbu { uint4 u[2]; unsigned short us[16]; };
    bbu bb;
    bb.u[0] = *(const uint4*)baddr;
    bb.u[1] = *(const uint4*)(baddr + 16);
    baddr += 128;

    for (int it = 0; it < 8; ++it) {
        const int cur = it & 1;
        __syncthreads();  // drains vmcnt: buf[cur] + bb are ready
        bbu bbc = bb;     // capture before overwriting with prefetch
        if (it < 7) {
#pragma unroll
            for (int i = 0; i < 2; ++i) {
                gl_lds16(kaddr[i], sK[cur ^ 1] + (i * 4 + w) * 1024);
                gl_lds16(vaddr[i], sV[cur ^ 1] + (i * 4 + w) * 1024);
                kaddr[i] += 8192;
                vaddr[i] += 128;
            }
            bb.u[0] = *(const uint4*)baddr;
            bb.u[1] = *(const uint4*)(baddr + 16);
            baddr += 128;
        }

        // QK^T (C-layout); q pre-scaled by 0.125
        f32x4 scv[4] = {};
#pragma unroll
        for (int tt = 0; tt < 4; ++tt)
#pragma unroll
            for (int ks = 0; ks < 2; ++ks) {
                int key = tt * 16 + ln;
                int c = ks * 4 + g;
                bf16x8 kf = *(const bf16x8*)(sK[cur] + key * 128 + (c ^ (key & 7)) * 16);
                scv[tt] = MFMA16(qf[ks], kf, scv[tt]);
            }

        cfence();
#pragma unroll
        for (int tt = 0; tt < 4; ++tt)
#pragma unroll
            for (int r = 0; r < 4; ++r)
                sc[(g * 4 + r) * 66 + tt * 16 + ln] = scv[tt][r];
        cfence();

        float sr[16];
        {
            const float* scrow = sc + qr * 66 + a * 16;
#pragma unroll
            for (int j = 0; j < 8; ++j) {
                float2 v2 = *(const float2*)(scrow + j * 2);
                sr[j * 2] = v2.x; sr[j * 2 + 1] = v2.y;
            }
        }
        cfence();

        // apply precomputed bias + magic mask + max
        float mx = -1e30f;
#pragma unroll
        for (int e = 0; e < 16; ++e) {
            unsigned int bits = bbc.us[e];
            float f = __uint_as_float(bits << 16);
            float s = sr[e] * f;
            s = (bits == 0xFF80u) ? -1e9f : s;
            sr[e] = s;
            mx = fmaxf(mx, s);
        }
        mx = fmaxf(mx, __shfl_xor(mx, 1));
        mx = fmaxf(mx, __shfl_xor(mx, 2));
        const float mnew = fmaxf(m_st, mx);
        const float alpha = __expf(m_st - mnew);
        m_st = mnew;
        float rs = 0.f;
        union { __hip_bfloat16 hh16[16]; uint4 u[2]; } Pk;
#pragma unroll
        for (int i = 0; i < 16; ++i) {
            float p = __expf(sr[i] - mnew);
            rs += p;
            Pk.hh16[i] = __float2bfloat16(p);
        }
        rs += __shfl_xor(rs, 1);
        rs += __shfl_xor(rs, 2);
        l_st = l_st * alpha + rs;

        *(uint4*)(sp + qr * 72 + a * 16) = Pk.u[0];
        *(uint4*)(sp + qr * 72 + a * 16 + 8) = Pk.u[1];
        cfence();

        if (a == 0) sBr[w][qr] = alpha;
        float al4[4];
#pragma unroll
        for (int r = 0; r < 4; ++r) al4[r] = sBr[w][g * 4 + r];
#pragma unroll
        for (int tt = 0; tt < 4; ++tt)
#pragma unroll
            for (int r = 0; r < 4; ++r) O[tt][r] *= al4[r];

        // PV
#pragma unroll
        for (int ks = 0; ks < 2; ++ks) {
            bf16x8 pf = *(const bf16x8*)(sp + ln * 72 + ks * 32 + g * 8);
#pragma unroll
            for (int tt = 0; tt < 4; ++tt) {
                int dk = tt * 16 + ln;
                int c = ks * 4 + g;
                bf16x8 vf = *(const bf16x8*)(sV[cur] + dk * 128 + (c ^ (dk & 7)) * 16);
                O[tt] = MFMA16(pf, vf, O[tt]);
            }
        }
        cfence();
    }

    // partial epilogue: unnormalized O (bf16) + (m,l) per row
    const size_t rowbase = ((size_t)spl * 32 + bh) * 1024 + q0 + w * 16;
    if (a == 0) {
        float2 ml2; ml2.x = m_st; ml2.y = l_st;
        Ml[rowbase + qr] = ml2;
    }
#pragma unroll
    for (int r = 0; r < 4; ++r) {
        const int q = g * 4 + r;
#pragma unroll
        for (int tt = 0; tt < 4; ++tt)
            Op[(rowbase + q) * 64 + tt * 16 + ln] = __float2bfloat16(O[tt][r]);
    }
}

// Merge the two key-splits (bf16 partials, f32 math).
// grid 4096 x 256 thr; thread = (row, dk pair).
__global__ __launch_bounds__(256) void combine(
    const __hip_bfloat16* __restrict__ Op, const float2* __restrict__ Ml,
    __hip_bfloat16* __restrict__ X) {
    const int idx = blockIdx.x * 256 + threadIdx.x;
    const int row = idx >> 5;
    const int pr = (idx & 31) * 2;
    float2 ml1 = Ml[row], ml2 = Ml[32768 + row];
    float m = fmaxf(ml1.x, ml2.x);
    float w1 = __expf(ml1.x - m), w2 = __expf(ml2.x - m);
    float inv = 1.f / fmaf(ml1.y, w1, ml2.y * w2);
    unsigned int u1 = *(const unsigned int*)(Op + (size_t)row * 64 + pr);
    unsigned int u2 = *(const unsigned int*)(Op + ((size_t)32768 + row) * 64 + pr);
    float o1x = __uint_as_float(u1 << 16), o1y = __uint_as_float(u1 & 0xFFFF0000u);
    float o2x = __uint_as_float(u2 << 16), o2y = __uint_as_float(u2 & 0xFFFF0000u);
    float x0 = fmaf(o1x, w1, o2x * w2) * inv;
    float x1 = fmaf(o1y, w1, o2y * w2) * inv;
    const int bh = row >> 10, s = row & 1023, b = bh >> 3, h = bh & 7;
    union { __hip_bfloat16 hh[2]; unsigned int u; } o;
    o.hh[0] = __float2bfloat16(x0);
    o.hh[1] = __float2bfloat16(x1);
    *(unsigned int*)(X + ((size_t)(b * 1024 + s)) * 512 + h * 64 + pr) = o.u;
}

extern "C" void kernel_launch(void* const* d_in, const int* in_sizes, int n_in,
                              void* d_out, int out_size, void* d_ws, size_t ws_size,
                              hipStream_t stream) {
    (void)in_sizes; (void)n_in; (void)out_size; (void)ws_size;
    const float* query = (const float*)d_in[0];
    const float* key   = (const float*)d_in[1];
    const float* value = (const float*)d_in[2];
    const float* dist  = (const float*)d_in[3];
    const int*   mask  = (const int*)d_in[4];
    const float* Wq = (const float*)d_in[5];
    const float* bq = (const float*)d_in[6];
    const float* Wk = (const float*)d_in[7];
    const float* bk = (const float*)d_in[8];
    const float* Wv = (const float*)d_in[9];
    const float* bv = (const float*)d_in[10];
    const float* Wo = (const float*)d_in[11];
    const float* bo = (const float*)d_in[12];
    const float* cw1 = (const float*)d_in[13];
    const float* cb1 = (const float*)d_in[14];
    const float* cw2 = (const float*)d_in[15];
    const float* cb2 = (const float*)d_in[16];
    float* out = (float*)d_out;

    char* ws = (char*)d_ws;
    const size_t MB = 1 << 20;
    __hip_bfloat16* qc  = (__hip_bfloat16*)(ws + 0 * MB);
    __hip_bfloat16* kc  = (__hip_bfloat16*)(ws + 4 * MB);
    __hip_bfloat16* vc  = (__hip_bfloat16*)(ws + 8 * MB);
    __hip_bfloat16* wqc = (__hip_bfloat16*)(ws + 12 * MB);
    __hip_bfloat16* wkc = (__hip_bfloat16*)(ws + 12 * MB + 512 * 1024);
    __hip_bfloat16* wvc = (__hip_bfloat16*)(ws + 13 * MB);
    __hip_bfloat16* woc = (__hip_bfloat16*)(ws + 13 * MB + 512 * 1024);
    __hip_bfloat16* qbh = (__hip_bfloat16*)(ws + 14 * MB);
    __hip_bfloat16* kbh = (__hip_bfloat16*)(ws + 18 * MB);
    __hip_bfloat16* vt  = (__hip_bfloat16*)(ws + 22 * MB);
    __hip_bfloat16* x   = (__hip_bfloat16*)(ws + 26 * MB);
    __hip_bfloat16* bS  = (__hip_bfloat16*)(ws + 32 * MB);  // 64 MB
    __hip_bfloat16* Op  = (__hip_bfloat16*)(ws + 96 * MB);  // 8.4 MB
    float2*         Ml  = (float2*)(ws + 112 * MB);         // 512 KB

    hipLaunchKernelGGL(prep, dim3(7680), dim3(256), 0, stream,
                       query, key, value, Wq, Wk, Wv, Wo, dist, mask,
                       cw1, cb1, cw2, cb2,
                       qc, kc, vc, wqc, wkc, wvc, woc, bS);
    hipLaunchKernelGGL(proj_gemm, dim3(4, 32, 3), dim3(256), 0, stream,
                       qc, kc, vc, wqc, wkc, wvc, bq, bk, bv, qbh, kbh, vt);
    hipLaunchKernelGGL(attn_split, dim3(16, 32, 2), dim3(256), 0, stream,
                       qbh, kbh, vt, bS, Op, Ml);
    hipLaunchKernelGGL(combine, dim3(4096), dim3(256), 0, stream, Op, Ml, x);
    hipLaunchKernelGGL(out_gemm, dim3(8, 32), dim3(256), 0, stream,
                       x, woc, bo, out);
}